// Round 6
// baseline (878.482 us; speedup 1.0000x reference)
//
#include <hip/hip_runtime.h>

#define D 128
#define SCAN_E 2048

typedef __attribute__((ext_vector_type(8))) short short8;
typedef __attribute__((ext_vector_type(8))) unsigned short ushort8v;
typedef __attribute__((ext_vector_type(4))) float floatx4;

__device__ __forceinline__ unsigned short f2bf(float x) {
    union { float f; unsigned u; } v; v.f = x;
    unsigned r = v.u + 0x7FFFu + ((v.u >> 16) & 1u);
    return (unsigned short)(r >> 16);
}
__device__ __forceinline__ float bf2f(unsigned short h) {
    union { float f; unsigned u; } v; v.u = ((unsigned)h) << 16;
    return v.f;
}
__device__ __forceinline__ void split2(float x, unsigned short& hi, unsigned short& lo) {
    hi = f2bf(x);
    lo = f2bf(x - bf2f(hi));
}
// NOTE: the 4th intrinsic arg (imm offset) applies to BOTH global and LDS addresses —
// never use it for global-only offsets; fold offsets into the global pointer instead.
__device__ __forceinline__ void load16(const void* g, void* l) {
    __builtin_amdgcn_global_load_lds((const __attribute__((address_space(1))) unsigned*)g,
                                     (__attribute__((address_space(3))) unsigned*)l, 16, 0, 0);
}

// counted-vmcnt pipeline fences (T4): wait for own loads, raw barrier, block compiler motion
#define WAITV(N) asm volatile("s_waitcnt vmcnt(" #N ")" ::: "memory")
#define BARX() do { asm volatile("" ::: "memory"); __builtin_amdgcn_s_barrier(); \
                    asm volatile("" ::: "memory"); __builtin_amdgcn_sched_barrier(0); } while (0)

// ---------- split-precision bf16 MFMA GEMM ----------
// C[M,NC] = A @ W^T (+bias); A as bf16 planes [M][256] = [Ah|Al], W as [NC][256] = [Wh|Wl].
// Effective K=384 bf16: Ah*Wh ; Al*Wh ; Ah*Wl  (error <= 2^-17).
// 128-B LDS rows: XOR swizzle c^=(r&7) is conflict-free (octet-distinct).
__global__ __launch_bounds__(256, 2)
void gemm_split(const unsigned short* __restrict__ Apl,
                const unsigned short* __restrict__ Wsp,
                const float* __restrict__ bias,
                float* __restrict__ Cf,            // fp32 out (or null)
                unsigned short* __restrict__ Cpl,  // bf16-plane out [M][256] (or null; NC==128 only)
                int M, int NC, int relu)
{
    __shared__ unsigned short sA[128 * 64];
    __shared__ unsigned short sW[128 * 64];
    const int t    = threadIdx.x;
    const int lane = t & 63;
    const int wv   = t >> 6;
    const int m0   = blockIdx.x * 128;
    const int n0   = blockIdx.y * 128;

    const int lrow  = lane >> 3;                         // 0..7
    const int scolb = (((lane & 7) ^ (lrow & 7)) << 4);  // pre-swizzled 16-B slot

    floatx4 acc[4][4];
    #pragma unroll
    for (int i = 0; i < 4; ++i)
        #pragma unroll
        for (int j = 0; j < 4; ++j)
            #pragma unroll
            for (int r = 0; r < 4; ++r) acc[i][j][r] = 0.f;

    for (int kk = 0; kk < 6; ++kk) {
        const int akb = ((kk < 4) ? kk : kk - 4) * 128;  // A row = 512 B: Ah,Al,Ah
        const int wkb = ((kk < 2) ? kk : kk - 2) * 128;  // W row = 512 B: Wh,Wh,Wl
        #pragma unroll
        for (int i = 0; i < 4; ++i) {
            const int rr = (wv * 4 + i) * 8 + lrow;      // 0..127 tile row
            int am = m0 + rr; if (am > M - 1) am = M - 1;
            load16((const char*)Apl + (size_t)am * 512 + akb + scolb,
                   (char*)sA + (size_t)(wv * 4 + i) * 1024);
            load16((const char*)Wsp + (size_t)(n0 + rr) * 512 + wkb + scolb,
                   (char*)sW + (size_t)(wv * 4 + i) * 1024);
        }
        __syncthreads();
        const int lane15 = lane & 15;
        const int quad   = lane >> 4;
        const int r7     = lane15 & 7;
        #pragma unroll
        for (int ks = 0; ks < 2; ++ks) {
            short8 a[4], b[4];
            const int sl = ((ks * 4 + quad) ^ r7) * 8;   // swizzled 8-short slot
            #pragma unroll
            for (int i = 0; i < 4; ++i)
                a[i] = *(const short8*)(sA + ((wv >> 1) * 64 + i * 16 + lane15) * 64 + sl);
            #pragma unroll
            for (int j = 0; j < 4; ++j)
                b[j] = *(const short8*)(sW + ((wv & 1) * 64 + j * 16 + lane15) * 64 + sl);
            #pragma unroll
            for (int i = 0; i < 4; ++i)
                #pragma unroll
                for (int j = 0; j < 4; ++j)
                    acc[i][j] = __builtin_amdgcn_mfma_f32_16x16x32_bf16(a[i], b[j], acc[i][j], 0, 0, 0);
        }
        __syncthreads();
    }

    const int lane15 = lane & 15;
    const int quad   = lane >> 4;
    #pragma unroll
    for (int i = 0; i < 4; ++i) {
        #pragma unroll
        for (int r = 0; r < 4; ++r) {
            const int m = m0 + (wv >> 1) * 64 + i * 16 + quad * 4 + r;
            if (m >= M) continue;
            #pragma unroll
            for (int j = 0; j < 4; ++j) {
                const int n = n0 + (wv & 1) * 64 + j * 16 + lane15;
                float v = acc[i][j][r] + (bias ? bias[n] : 0.f);
                if (relu) v = fmaxf(v, 0.f);
                if (Cf) Cf[(size_t)m * NC + n] = v;
                if (Cpl) {
                    unsigned short hi, lo; split2(v, hi, lo);
                    Cpl[(size_t)m * 256 + n] = hi;
                    Cpl[(size_t)m * 256 + 128 + n] = lo;
                }
            }
        }
    }
}

// ---------- fused dual-GEMM + GRU v6: counted-vmcnt pipeline ----------
// grid (ceil(N/64), 2); 256 thr; 64 rows x 64 channels (col-half h).
// 8 chunks: 0-3 stage {Ah,Al,Hh,Hl}+{Wi_hi,Wh_hi} -> 48 MFMA/wave;
//           4-7 stage {Ah,Hh}+{Wi_lo,Wh_lo} -> 24 MFMA/wave.  (Wh plane staged ONCE.)
// Schedule per chunk P: waitcnt vmcnt(n(P+1)) ; barrier ; compute P ; barrier ; stage P+2.
// Each wave waits only for ITS chunk-P loads (A-waves 8/4, W-waves 12); chunk P+1's
// loads stay in flight ACROSS the barrier (no vmcnt(0) drain in the loop).
// LDS per buf (shorts): Ah 0 | Al 2048 | Hh 4096 | Hl 6144 | Wi 8192 | Wh 14336. 2x40 KB.
template<int P>
__device__ __forceinline__ void gg_stage(char* L, int wv,
    const char* const (&ab)[4], const char* const (&wp)[12])
{
    constexpr int ahi = (P < 4 ? P : P - 4) * 64;
    constexpr int alo = 256 + (P < 4 ? P : 0) * 64;
    constexpr int wof = (P < 4) ? P * 64 : 256 + (P - 4) * 64;
    if (wv < 2) {
        char* dst = L + (wv ? 8192 : 0);
        #pragma unroll
        for (int i = 0; i < 4; ++i) {
            load16(ab[i] + ahi, dst + i * 1024);
            if constexpr (P < 4) load16(ab[i] + alo, dst + 4096 + i * 1024);
        }
    } else {
        char* dst = L + (wv == 2 ? 16384 : 28672);
        #pragma unroll
        for (int j = 0; j < 12; ++j)
            load16(wp[j] + wof, dst + j * 1024);
    }
}

template<bool FULL>
__device__ __forceinline__ void gg_compute(const unsigned short* B, int lane15, int sl, int wc,
    floatx4 (&arz)[2][4], floatx4 (&ain)[4], floatx4 (&ahn)[4])
{
    short8 ah[4], hh[4], al[4], hl[4];
    #pragma unroll
    for (int i = 0; i < 4; ++i) {
        const int ar = (i * 16 + lane15) * 32;
        ah[i] = *(const short8*)(B + ar + sl);
        hh[i] = *(const short8*)(B + 4096 + ar + sl);
        if constexpr (FULL) {
            al[i] = *(const short8*)(B + 2048 + ar + sl);
            hl[i] = *(const short8*)(B + 6144 + ar + sl);
        }
    }
    __builtin_amdgcn_s_setprio(1);
    #pragma unroll
    for (int j = 0; j < 2; ++j) {
        const int wr = (wc * 48 + j * 16 + lane15) * 32;
        const short8 bi = *(const short8*)(B + 8192 + wr + sl);
        const short8 bh = *(const short8*)(B + 14336 + wr + sl);
        #pragma unroll
        for (int i = 0; i < 4; ++i) {
            arz[j][i] = __builtin_amdgcn_mfma_f32_16x16x32_bf16(ah[i], bi, arz[j][i], 0, 0, 0);
            arz[j][i] = __builtin_amdgcn_mfma_f32_16x16x32_bf16(hh[i], bh, arz[j][i], 0, 0, 0);
            if constexpr (FULL) {
                arz[j][i] = __builtin_amdgcn_mfma_f32_16x16x32_bf16(al[i], bi, arz[j][i], 0, 0, 0);
                arz[j][i] = __builtin_amdgcn_mfma_f32_16x16x32_bf16(hl[i], bh, arz[j][i], 0, 0, 0);
            }
        }
    }
    {
        const int wr = (wc * 48 + 32 + lane15) * 32;
        const short8 bi = *(const short8*)(B + 8192 + wr + sl);
        const short8 bh = *(const short8*)(B + 14336 + wr + sl);
        #pragma unroll
        for (int i = 0; i < 4; ++i) {
            ain[i] = __builtin_amdgcn_mfma_f32_16x16x32_bf16(ah[i], bi, ain[i], 0, 0, 0);
            ahn[i] = __builtin_amdgcn_mfma_f32_16x16x32_bf16(hh[i], bh, ahn[i], 0, 0, 0);
            if constexpr (FULL) {
                ain[i] = __builtin_amdgcn_mfma_f32_16x16x32_bf16(al[i], bi, ain[i], 0, 0, 0);
                ahn[i] = __builtin_amdgcn_mfma_f32_16x16x32_bf16(hl[i], bh, ahn[i], 0, 0, 0);
            }
        }
    }
    __builtin_amdgcn_s_setprio(0);
}

__device__ __forceinline__ void hold_stage(char* L0, const unsigned short* Hcur,
                                           int wv, int lane, int m0, int M, int h)
{
    #pragma unroll
    for (int j = 0; j < 4; ++j) {
        const int p   = (wv * 4 + j) * 512 + lane * 8;   // short index in E
        const int row = p >> 7;
        const int seg = (lane & 15) * 8;
        int gm = m0 + row; if (gm > M - 1) gm = M - 1;
        const size_t gb = (size_t)gm * 512 +
            (seg < 64 ? (size_t)(h * 128 + seg * 2) : (size_t)(256 + h * 128 + (seg - 64) * 2));
        load16((const char*)Hcur + gb, L0 + (size_t)p * 2);
    }
}

#define WA(NA, NW) do { if (wv < 2) { WAITV(NA); } else { WAITV(NW); } } while (0)

__global__ __launch_bounds__(256, 2)
void gru_gemm(const unsigned short* __restrict__ Apl,   // agg planes [N][256]
              const unsigned short* __restrict__ Hcur,  // h planes in  [N][256]
              unsigned short* __restrict__ Hnxt,         // h planes out [N][256]
              const unsigned short* __restrict__ Wi,     // split permuted fused Wih@Wc [384][256]
              const unsigned short* __restrict__ Wh,     // split permuted Whh        [384][256]
              const float* __restrict__ bih, const float* __restrict__ bhh,
              int M, int relu)
{
    __shared__ unsigned short lds[2][20480];   // 2 x 40 KB
    const int t    = threadIdx.x;
    const int lane = t & 63;
    const int wv   = t >> 6;        // 0..3 = wc (col wave)
    const int wc   = wv;
    const int m0   = blockIdx.x * 64;
    const int h    = blockIdx.y;    // column half

    const int lrow  = lane >> 2;                                // 0..15
    const int scolb = (((lane & 3) ^ ((lrow >> 1) & 3)) << 4);  // 64-B-row swizzle

    // per-lane source row base pointers (computed once)
    const char* ab[4];
    const char* wp[12];
    if (wv < 2) {
        const char* srcp = wv ? (const char*)Hcur : (const char*)Apl;
        #pragma unroll
        for (int i = 0; i < 4; ++i) {
            int am = m0 + i * 16 + lrow; if (am > M - 1) am = M - 1;
            ab[i] = srcp + (size_t)am * 512 + scolb;
        }
        #pragma unroll
        for (int j = 0; j < 12; ++j) wp[j] = srcp;
    } else {
        const char* srcp = (wv == 2) ? (const char*)Wi : (const char*)Wh;
        #pragma unroll
        for (int j = 0; j < 12; ++j)
            wp[j] = srcp + (size_t)(h * 192 + j * 16 + lrow) * 512 + scolb;
        #pragma unroll
        for (int i = 0; i < 4; ++i) ab[i] = srcp;
    }

    floatx4 arz[2][4], ain[4], ahn[4];
    #pragma unroll
    for (int i = 0; i < 4; ++i)
        #pragma unroll
        for (int r = 0; r < 4; ++r) {
            arz[0][i][r] = 0.f; arz[1][i][r] = 0.f;
            ain[i][r] = 0.f; ahn[i][r] = 0.f;
        }

    const int lane15 = lane & 15;
    const int quad   = lane >> 4;
    const int sl     = ((quad ^ ((lane15 >> 1) & 3)) << 3);  // swizzled 8-short slot

    char* L0 = (char*)&lds[0][0];
    char* L1 = (char*)&lds[1][0];
    const unsigned short* B0 = &lds[0][0];
    const unsigned short* B1 = &lds[1][0];

    // ---- counted-vmcnt pipeline: chunk P+1 loads stay in flight across barriers ----
    gg_stage<0>(L0, wv, ab, wp);
    gg_stage<1>(L1, wv, ab, wp);
    WA(8, 12);  BARX();  gg_compute<true >(B0, lane15, sl, wc, arz, ain, ahn);  BARX();  gg_stage<2>(L0, wv, ab, wp);
    WA(8, 12);  BARX();  gg_compute<true >(B1, lane15, sl, wc, arz, ain, ahn);  BARX();  gg_stage<3>(L1, wv, ab, wp);
    WA(8, 12);  BARX();  gg_compute<true >(B0, lane15, sl, wc, arz, ain, ahn);  BARX();  gg_stage<4>(L0, wv, ab, wp);
    WA(4, 12);  BARX();  gg_compute<true >(B1, lane15, sl, wc, arz, ain, ahn);  BARX();  gg_stage<5>(L1, wv, ab, wp);
    WA(4, 12);  BARX();  gg_compute<false>(B0, lane15, sl, wc, arz, ain, ahn);  BARX();  gg_stage<6>(L0, wv, ab, wp);
    WA(4, 12);  BARX();  gg_compute<false>(B1, lane15, sl, wc, arz, ain, ahn);  BARX();  gg_stage<7>(L1, wv, ab, wp);
    WA(4, 12);  BARX();  gg_compute<false>(B0, lane15, sl, wc, arz, ain, ahn);  BARX();  hold_stage(L0, Hcur, wv, lane, m0, M, h);
    WAITV(4);   BARX();  gg_compute<false>(B1, lane15, sl, wc, arz, ain, ahn);
    WAITV(0);   BARX();

    // ---- epilogue: GRU against LDS-staged hold, coalesced writeback ----
    unsigned short* E = &lds[0][0];            // [64 rows][128 shorts] = hi(64)|lo(64)
    const int cl = wc * 16 + lane15;           // 0..63 local channel
    const int cg = h * 64 + cl;                // global channel
    const float bi0 = bih[cg], bi1 = bih[128 + cg], bi2 = bih[256 + cg];
    const float bh0 = bhh[cg], bh1 = bhh[128 + cg], bh2 = bhh[256 + cg];

    #pragma unroll
    for (int i = 0; i < 4; ++i) {
        #pragma unroll
        for (int r = 0; r < 4; ++r) {
            const int mrow = i * 16 + quad * 4 + r;
            unsigned short* eh = E + mrow * 128 + cl;
            const float hold = bf2f(eh[0]) + bf2f(eh[64]);
            const float rr  = arz[0][i][r] + bi0 + bh0;
            const float zz  = arz[1][i][r] + bi1 + bh1;
            const float in_ = ain[i][r] + bi2;
            const float hn  = ahn[i][r] + bh2;
            const float rg = 1.f / (1.f + __expf(-rr));
            const float zg = 1.f / (1.f + __expf(-zz));
            const float e2 = __expf(2.f * (in_ + rg * hn));
            const float ng = 1.f - 2.f / (e2 + 1.f);          // tanh via exp (VALU-cheap)
            float v = (1.f - zg) * ng + zg * hold;
            if (relu) v = fmaxf(v, 0.f);
            unsigned short hi, lo; split2(v, hi, lo);
            eh[0]  = hi;
            eh[64] = lo;
        }
    }
    __syncthreads();

    #pragma unroll
    for (int j = 0; j < 4; ++j) {
        const int p   = (wv * 4 + j) * 512 + lane * 8;
        const int row = p >> 7;
        const int m   = m0 + row;
        if (m < M) {
            const int seg = (lane & 15) * 8;
            const size_t gb = (size_t)m * 512 +
                (seg < 64 ? (size_t)(h * 128 + seg * 2) : (size_t)(256 + h * 128 + (seg - 64) * 2));
            *(ushort8v*)((char*)Hnxt + gb) = *(const ushort8v*)(E + p);
        }
    }
}

// ---------- weight fuse: Wf[l] = Wih @ Wconv[l]  ([384,128] = [384,128]@[128,128]) ----------
__global__ __launch_bounds__(256)
void fuse_w(const float* __restrict__ Wih, const float* __restrict__ Wconv,
            float* __restrict__ Wf)
{
    const int l = blockIdx.y;
    const int o = blockIdx.x * 2 + (threadIdx.x >> 7);
    const int k = threadIdx.x & 127;
    const float* wih = Wih + (size_t)o * 128;
    const float* wcc = Wconv + (size_t)l * 16384 + k;
    float s = 0.f;
    #pragma unroll 8
    for (int j = 0; j < 128; ++j) s += wih[j] * wcc[(size_t)j * 128];
    Wf[(size_t)l * 49152 + (size_t)o * 128 + k] = s;
}

// ---------- splitting: rows of 128 fp32 -> [hi|lo] planes (256 shorts/row) ----------
__global__ __launch_bounds__(256)
void split_act(const float* __restrict__ A, unsigned short* __restrict__ out, int total)
{
    const int tid = blockIdx.x * 256 + threadIdx.x;
    if (tid >= total) return;
    const int n = tid >> 7, k = tid & 127;
    unsigned short hi, lo; split2(A[tid], hi, lo);
    out[(size_t)n * 256 + k]       = hi;
    out[(size_t)n * 256 + 128 + k] = lo;
}

// split with 16-channel gate-interleave row permutation (input [384][128]):
// row o = g*128 + c  ->  op = (c/16)*48 + g*16 + (c%16)
__global__ __launch_bounds__(256)
void split_wt_g(const float* __restrict__ W, unsigned short* __restrict__ out)
{
    const int tid = blockIdx.x * 256 + threadIdx.x;    // over 384*128 exactly
    const int o = tid >> 7, k = tid & 127;
    const int g = o >> 7, c = o & 127;                 // gate, channel
    const int op = (c >> 4) * 48 + g * 16 + (c & 15);  // permuted row
    unsigned short hi, lo; split2(W[tid], hi, lo);
    out[(size_t)op * 256 + k]       = hi;
    out[(size_t)op * 256 + 128 + k] = lo;
}

// ---------- CSR build ----------
__global__ __launch_bounds__(256)
void count_dst(const int* __restrict__ dst, int* __restrict__ counts, int E, int N)
{
    const int e = blockIdx.x * 256 + threadIdx.x;
    if (e >= E) return;
    const int d = dst[e];
    if ((unsigned)d < (unsigned)N) atomicAdd(&counts[d], 1);
}

__global__ __launch_bounds__(256)
void scan_block(const int* __restrict__ counts, int* __restrict__ rowptr,
                int* __restrict__ partials, int N)
{
    __shared__ int sT[256];
    const int t = threadIdx.x;
    const int base = blockIdx.x * SCAN_E + t * 8;
    int v[8]; int s = 0;
    #pragma unroll
    for (int i = 0; i < 8; ++i) {
        const int idx = base + i;
        v[i] = (idx < N) ? counts[idx] : 0;
        s += v[i];
    }
    sT[t] = s;
    __syncthreads();
    for (int off = 1; off < 256; off <<= 1) {
        int x = (t >= off) ? sT[t - off] : 0;
        __syncthreads();
        sT[t] += x;
        __syncthreads();
    }
    if (t == 255) partials[blockIdx.x] = sT[255];
    int run = sT[t] - s;
    #pragma unroll
    for (int i = 0; i < 8; ++i) {
        const int idx = base + i;
        if (idx < N) rowptr[idx] = run;
        run += v[i];
    }
}

__global__ void scan_partials(int* __restrict__ partials, int nb,
                              int* __restrict__ rowptr, int N)
{
    if (threadIdx.x == 0 && blockIdx.x == 0) {
        int run = 0;
        for (int i = 0; i < nb; ++i) { int c = partials[i]; partials[i] = run; run += c; }
        rowptr[N] = run;
    }
}

__global__ __launch_bounds__(256)
void add_offsets(int* __restrict__ rowptr, const int* __restrict__ partials,
                 int* __restrict__ cursor, int N)
{
    const int off  = partials[blockIdx.x];
    const int base = blockIdx.x * SCAN_E + threadIdx.x * 8;
    #pragma unroll
    for (int i = 0; i < 8; ++i) {
        const int idx = base + i;
        if (idx < N) { const int r = rowptr[idx] + off; rowptr[idx] = r; cursor[idx] = r; }
    }
}

__global__ __launch_bounds__(256)
void fill_csr(const int* __restrict__ src, const int* __restrict__ dst,
              int* __restrict__ cursor, int* __restrict__ eidx, int E, int N)
{
    const int e = blockIdx.x * 256 + threadIdx.x;
    if (e >= E) return;
    const int d = dst[e], s = src[e];
    if ((unsigned)d >= (unsigned)N || (unsigned)s >= (unsigned)N) return;
    const int slot = atomicAdd(&cursor[d], 1);
    eidx[slot] = s;
}

// ---------- gather: aggpl = planes(segment_sum(h[src])) ----------
// 32 lanes/node; each lane one 16-B load per edge (lanes 0-15 hi plane, 16-31 lo);
// 2-edge unroll; shfl_down(16) hi+lo combine.
__global__ __launch_bounds__(256)
void gather_sum_h(const unsigned short* __restrict__ hpl, const int* __restrict__ rowptr,
                  const int* __restrict__ eidx, unsigned short* __restrict__ aggpl, int N)
{
    const int tid  = blockIdx.x * 256 + threadIdx.x;
    const int node = tid >> 5;
    const int lane = tid & 31;
    if (node >= N) return;
    const int beg = rowptr[node];
    const int end = rowptr[node + 1];
    float acc[8];
    #pragma unroll
    for (int c = 0; c < 8; ++c) acc[c] = 0.f;
    int e = beg;
    for (; e + 2 <= end; e += 2) {
        const int s0 = eidx[e], s1 = eidx[e + 1];
        const ushort8v v0 = *(const ushort8v*)(hpl + (size_t)s0 * 256 + lane * 8);
        const ushort8v v1 = *(const ushort8v*)(hpl + (size_t)s1 * 256 + lane * 8);
        #pragma unroll
        for (int c = 0; c < 8; ++c) acc[c] += bf2f(v0[c]) + bf2f(v1[c]);
    }
    if (e < end) {
        const int s0 = eidx[e];
        const ushort8v v0 = *(const ushort8v*)(hpl + (size_t)s0 * 256 + lane * 8);
        #pragma unroll
        for (int c = 0; c < 8; ++c) acc[c] += bf2f(v0[c]);
    }
    #pragma unroll
    for (int c = 0; c < 8; ++c) acc[c] += __shfl_down(acc[c], 16);
    if (lane < 16) {
        ushort8v hi8, lo8;
        #pragma unroll
        for (int c = 0; c < 8; ++c) {
            unsigned short hi, lo; split2(acc[c], hi, lo);
            hi8[c] = hi; lo8[c] = lo;
        }
        *(ushort8v*)(aggpl + (size_t)node * 256 + lane * 8)       = hi8;
        *(ushort8v*)(aggpl + (size_t)node * 256 + 128 + lane * 8) = lo8;
    }
}

extern "C" void kernel_launch(void* const* d_in, const int* in_sizes, int n_in,
                              void* d_out, int out_size, void* d_ws, size_t ws_size,
                              hipStream_t stream)
{
    const float* x     = (const float*)d_in[0];
    const int*   edges = (const int*)  d_in[1];
    const float* W1    = (const float*)d_in[2];
    const float* b1    = (const float*)d_in[3];
    const float* Wconv = (const float*)d_in[4];
    const float* Wih   = (const float*)d_in[5];
    const float* Whh   = (const float*)d_in[6];
    const float* bih   = (const float*)d_in[7];
    const float* bhh   = (const float*)d_in[8];
    const float* W2    = (const float*)d_in[9];
    const float* b2    = (const float*)d_in[10];
    float* out = (float*)d_out;

    const int N = in_sizes[0] / D;   // 100000
    const int E = in_sizes[1] / 2;   // 600000

    // ---- workspace layout (~160 MB) ----
    char* base = (char*)d_ws;
    const size_t szH = (size_t)N * 256 * 2;                       // 51.2 MB per plane buffer
    unsigned short* hA     = (unsigned short*)base;
    unsigned short* hB     = (unsigned short*)(base + szH);
    unsigned short* agg_pl = (unsigned short*)(base + 2 * szH);
    char* wb = base + 3 * szH;
    unsigned short* W1s  = (unsigned short*)wb;                   // 128*256
    unsigned short* W2s  = W1s  + (size_t)128 * 256;              // 384*256
    unsigned short* Whhs = W2s  + (size_t)384 * 256;              // 384*256 (permuted)
    unsigned short* Wfs  = Whhs + (size_t)384 * 256;              // 3 * 384*256 (permuted fused)
    float* Wfb = (float*)(Wfs + (size_t)3 * 384 * 256);           // 3*384*128 fp32 temp
    int* rowptr   = (int*)((char*)Wfb + (size_t)3 * 384 * 128 * 4);
    int* counts   = rowptr + N + 1;                               // doubles as cursor
    int* partials = counts + N;
    int* eidx     = partials + 64;
    unsigned short* x_pl = agg_pl;   // alias: x planes dead before first gather writes agg

    const int* src = edges;
    const int* dst = edges + E;

    const dim3 blk(256);
    const int mb   = (N + 127) / 128;               // 782
    const int mb64 = (N + 63) / 64;                 // 1563
    const int nb = (N + SCAN_E - 1) / SCAN_E;

    // ---- weight prep ----
    split_act<<<dim3(64),  blk, 0, stream>>>(W1, W1s, 128 * 128);
    split_act<<<dim3(192), blk, 0, stream>>>(W2, W2s, 384 * 128);
    fuse_w<<<dim3(192, 3), blk, 0, stream>>>(Wih, Wconv, Wfb);
    for (int l = 0; l < 3; ++l)
        split_wt_g<<<dim3(192), blk, 0, stream>>>(Wfb + (size_t)l * 49152,
                                                  Wfs + (size_t)l * 98304);
    split_wt_g<<<dim3(192), blk, 0, stream>>>(Whh, Whhs);
    split_act<<<dim3((N * 128 + 255) / 256), blk, 0, stream>>>(x, x_pl, N * 128);

    // ---- build CSR (dst-bucketed) once ----
    hipMemsetAsync(counts, 0, (size_t)N * sizeof(int), stream);
    count_dst<<<dim3((E + 255) / 256), blk, 0, stream>>>(dst, counts, E, N);
    scan_block<<<dim3(nb), blk, 0, stream>>>(counts, rowptr, partials, N);
    scan_partials<<<dim3(1), dim3(64), 0, stream>>>(partials, nb, rowptr, N);
    add_offsets<<<dim3(nb), blk, 0, stream>>>(rowptr, partials, counts, N);
    fill_csr<<<dim3((E + 255) / 256), blk, 0, stream>>>(src, dst, counts, eidx, E, N);

    // ---- h = relu(x @ W1^T + b1), stored as planes only ----
    gemm_split<<<dim3(mb, 1), blk, 0, stream>>>(x_pl, W1s, b1, nullptr, hA, N, 128, 1);

    // ---- layers: gather(h) then fused dual-GEMM + GRU (ping-pong h) ----
    unsigned short* hcur = hA;
    unsigned short* hnxt = hB;
    for (int l = 0; l < 3; ++l) {
        gather_sum_h<<<dim3((N * 32 + 255) / 256), blk, 0, stream>>>(hcur, rowptr, eidx, agg_pl, N);
        gru_gemm<<<dim3(mb64, 2), blk, 0, stream>>>(agg_pl, hcur, hnxt,
                                                    Wfs + (size_t)l * 98304, Whhs,
                                                    bih, bhh, N, l == 2);
        unsigned short* tmp = hcur; hcur = hnxt; hnxt = tmp;
    }

    // ---- out = relu(h) @ W2^T + b2 (relu already applied in planes) ----
    gemm_split<<<dim3(mb, 3), blk, 0, stream>>>(hcur, W2s, b2, out, nullptr, N, 384, 0);
}